// Round 9
// baseline (160.309 us; speedup 1.0000x reference)
//
#include <hip/hip_runtime.h>
#include <math.h>

// Problem constants (match reference)
#define T_LEN 4096
#define FIR_L 513
#define N_PHA 10
#define N_AMP 10
#define N_BANDS 20
#define N_BINS 18
#define BC 64            // B*C = 4*16

typedef __attribute__((ext_vector_type(8))) short short8;
typedef __attribute__((ext_vector_type(4))) float f32x4;

// Interleaved-complex skewed addresses (float index of re; im at +1).
// Extents: ZA(4095)+2 = 8702 -> z region 8704 floats; TA(255)+2 = 542 floats.
#define ZA(i) (((i) << 1) + ((((i) >> 4)) << 1))
#define TA(m) (((m) << 1) + ((((m) >> 4)) << 1))

// Rotation constants W^r = e^{i r*2pi/4096} components (cos, sin)
#define C1R 0.9999988234517019f
#define S1R 0.0015339801862847655f
#define C2R 0.9999952938095762f
#define S2R 0.0030679567629659760f
#define C3R 0.9999894107520978f
#define S3R 0.0046019261204485710f

// float -> bf16 round-to-nearest-even
static __device__ __forceinline__ unsigned short f2bf(float x) {
    unsigned u = __float_as_uint(x);
    unsigned r = u + 0x7FFFu + ((u >> 16) & 1u);
    return (unsigned short)(r >> 16);
}

// storage index <-> frequency after radix-4 DIF (base-4 digit reversal, involution)
static __device__ __forceinline__ int digitrev12(int p) {
    unsigned rr = __brev((unsigned)p) >> 20;               // 12-bit bit reversal
    rr = ((rr & 0x555u) << 1) | ((rr & 0xAAAu) >> 1);      // swap bit pairs
    return (int)rr;
}

// fetch W^m1 from 256-entry table of W^{4k}; derive odd residues when fine.
static __device__ __forceinline__ void tw_fetch(const float* tw, int m1, bool fine,
                                                float& c1, float& s1) {
    if (fine) {
        const int b = m1 >> 2, r = m1 & 3;
        const float2 w4 = *(const float2*)&tw[TA(b)];
        const float rc = (r & 2) ? ((r & 1) ? C3R : C2R) : ((r & 1) ? C1R : 1.0f);
        const float rs = (r & 2) ? ((r & 1) ? S3R : S2R) : ((r & 1) ? S1R : 0.0f);
        c1 = w4.x * rc - w4.y * rs;
        s1 = w4.y * rc + w4.x * rs;
    } else {
        const float2 w4 = *(const float2*)&tw[TA(m1 >> 2)];
        c1 = w4.x; s1 = w4.y;
    }
}

// Forward radix-4 DIF, natural -> base-4 digit-reversed.
static __device__ __forceinline__ void fft_fwd6(float* z, const float* tw, int tid) {
    for (int s = 0; s < 6; ++s) {
        const int hl = 10 - 2 * s;
        const int h  = 1 << hl;
        const bool fine = (s == 0);   // m1 = k<<2s may be non-multiple-of-4
#pragma unroll
        for (int r = 0; r < 4; ++r) {
            const int u  = tid + (r << 8);
            const int k  = u & (h - 1);
            const int g  = u >> hl;
            const int i0 = (g << (hl + 2)) + k;
            const int m1 = k << (2 * s);                 // < 1024
            float c1, s1;
            tw_fetch(tw, m1, fine, c1, s1);
            const float s2 = 2.0f * s1 * c1;             // double angle
            const float c2 = fmaf(-2.0f * s1, s1, 1.0f);
            const float c3 = c1 * c2 - s1 * s2;          // angle sum
            const float s3 = s1 * c2 + c1 * s2;

            float2 a = *(const float2*)&z[ZA(i0)];
            float2 b = *(const float2*)&z[ZA(i0 + h)];
            float2 c = *(const float2*)&z[ZA(i0 + 2 * h)];
            float2 d = *(const float2*)&z[ZA(i0 + 3 * h)];

            const float t0r = a.x + c.x, t0i = a.y + c.y;
            const float t1r = a.x - c.x, t1i = a.y - c.y;
            const float t2r = b.x + d.x, t2i = b.y + d.y;
            const float t3r = b.x - d.x, t3i = b.y - d.y;

            const float y0r = t0r + t2r,  y0i = t0i + t2i;
            const float u1r = t1r + t3i, u1i = t1i - t3r;   // t1 - i*t3
            const float u2r = t0r - t2r, u2i = t0i - t2i;
            const float u3r = t1r - t3i, u3i = t1i + t3r;   // t1 + i*t3
            const float y1r = u1r * c1 + u1i * s1, y1i = u1i * c1 - u1r * s1;
            const float y2r = u2r * c2 + u2i * s2, y2i = u2i * c2 - u2r * s2;
            const float y3r = u3r * c3 + u3i * s3, y3i = u3i * c3 - u3r * s3;

            *(float2*)&z[ZA(i0)]         = make_float2(y0r, y0i);
            *(float2*)&z[ZA(i0 + h)]     = make_float2(y1r, y1i);
            *(float2*)&z[ZA(i0 + 2 * h)] = make_float2(y2r, y2i);
            *(float2*)&z[ZA(i0 + 3 * h)] = make_float2(y3r, y3i);
        }
        __syncthreads();
    }
}

// Inverse radix-4 DIT, base-4 digit-reversed -> natural (unscaled).
static __device__ __forceinline__ void fft_inv6(float* z, const float* tw, int tid) {
    for (int s = 0; s < 6; ++s) {
        const int hl = 2 * s;
        const int L  = 1 << hl;
        const bool fine = (s == 5);   // m1 = k<<(10-hl), shift 0 at s=5
#pragma unroll
        for (int r = 0; r < 4; ++r) {
            const int u  = tid + (r << 8);
            const int k  = u & (L - 1);
            const int g  = u >> hl;
            const int i0 = (g << (hl + 2)) + k;
            const int m1 = k << (10 - hl);               // < 1024
            float c1, s1;
            tw_fetch(tw, m1, fine, c1, s1);
            const float s2 = 2.0f * s1 * c1;
            const float c2 = fmaf(-2.0f * s1, s1, 1.0f);
            const float c3 = c1 * c2 - s1 * s2;
            const float s3 = s1 * c2 + c1 * s2;

            float2 a = *(const float2*)&z[ZA(i0)];
            float2 b = *(const float2*)&z[ZA(i0 + L)];
            float2 c = *(const float2*)&z[ZA(i0 + 2 * L)];
            float2 d = *(const float2*)&z[ZA(i0 + 3 * L)];

            const float tbr = b.x * c1 - b.y * s1, tbi = b.y * c1 + b.x * s1;
            const float tcr = c.x * c2 - c.y * s2, tci = c.y * c2 + c.x * s2;
            const float tdr = d.x * c3 - d.y * s3, tdi = d.y * c3 + d.x * s3;

            const float y0r = a.x + tbr + tcr + tdr;
            const float y0i = a.y + tbi + tci + tdi;
            const float y1r = a.x - tbi - tcr + tdi;
            const float y1i = a.y + tbr - tci - tdr;
            const float y2r = a.x - tbr + tcr - tdr;
            const float y2i = a.y - tbi + tci - tdi;
            const float y3r = a.x + tbi - tcr - tdi;
            const float y3i = a.y - tbr - tci + tdr;

            *(float2*)&z[ZA(i0)]         = make_float2(y0r, y0i);
            *(float2*)&z[ZA(i0 + L)]     = make_float2(y1r, y1i);
            *(float2*)&z[ZA(i0 + 2 * L)] = make_float2(y2r, y2i);
            *(float2*)&z[ZA(i0 + 3 * L)] = make_float2(y3r, y3i);
        }
        __syncthreads();
    }
}

// ---------------------------------------------------------------------------
// Precompute: blocks 0..63 -> X[bc]; blocks 64..83 -> Hf[band] (corr kernel
// h[n]=f[256-n] circular). Spectra stored in NATURAL frequency order.
// Filter staging needs only 3 scalars/thread -> direct global loads, no LDS.
// ---------------------------------------------------------------------------
__global__ __launch_bounds__(256) void spectral_pre(
    const float* __restrict__ x,      // (BC, T)
    const float* __restrict__ filt,   // (20, 513)
    float2* __restrict__ Xs,          // (BC, 4096) natural freq order
    float2* __restrict__ Hs)          // (20, 4096) natural freq order
{
    __shared__ float smem[8704 + 542];   // z | tw4 -> 37.0 KB
    float* z  = smem;
    float* tw = smem + 8704;

    const int tid = threadIdx.x;
    const int b   = blockIdx.x;

    if (tid < 256) {   // tw4[k] = (cos,sin) of 2*pi*k/1024
        float ang = (float)tid * (6.283185307179586f / 1024.0f);
        float s, c;
        sincosf(ang, &s, &c);
        tw[TA(tid)]     = c;
        tw[TA(tid) + 1] = s;
    }

    if (b < BC) {
        const float* xrow = x + b * T_LEN;
        for (int i = tid; i < 4096; i += 256)
            *(float2*)&z[ZA(i)] = make_float2(xrow[i], 0.0f);
    } else {
        const float* frow = filt + (b - BC) * FIR_L;
        const float fa  = frow[256 - tid];   // for i = tid       (h = f[256-i])
        const float fbv = frow[512 - tid];   // for i = 3840+tid  (h = f[4352-i])
        const float fc  = frow[0];           // for i = 256 (tid 0 only)
#pragma unroll
        for (int k = 0; k < 16; ++k) {
            const int i = (k << 8) + tid;
            float hv = 0.0f;
            if (k == 0)  hv = fa;
            if (k == 1 && tid == 0) hv = fc;
            if (k == 15) hv = fbv;
            *(float2*)&z[ZA(i)] = make_float2(hv, 0.0f);
        }
    }
    __syncthreads();

    fft_fwd6(z, tw, tid);

    float2* dst = (b < BC) ? (Xs + b * 4096) : (Hs + (b - BC) * 4096);
    for (int i = tid; i < 4096; i += 256)
        dst[digitrev12(i)] = *(const float2*)&z[ZA(i)];   // natural order
}

// ---------------------------------------------------------------------------
// Main: per (bc, band-pair j/j+10): pack corr_a + i*corr_b into ONE fwd FFT;
// half-spectrum Hermitian split + masked products (Pb in 16 VGPRs); two
// inverse FFTs. LDS 37 KB -> 4 blocks/CU -> all 640 blocks co-resident.
// xe/fb0/fb1 alias the z region (dead before z is first written).
// ---------------------------------------------------------------------------
__global__ __launch_bounds__(256) void spectral_main(
    const float* __restrict__ x,          // (BC, T)
    const float* __restrict__ filt,       // (20, 513)
    const float2* __restrict__ Xs,        // (BC, 4096) natural order
    const float2* __restrict__ Hs,        // (20, 4096) natural order
    float* __restrict__ pha,              // (BC, 10, T) fp32
    unsigned short* __restrict__ amp_bf)  // (BC, 10, T) bf16 bits
{
    __shared__ float smem[8704 + 542];   // z | tw4 -> 37.0 KB
    float* z   = smem;
    float* tw  = smem + 8704;
    float* xe  = smem;          // 512  (aliases z, used only pre-FFT)
    float* fb0 = smem + 512;    // 513
    float* fb1 = smem + 1025;   // 513

    const int tid = threadIdx.x;
    const int bc  = blockIdx.x / N_PHA;
    const int j   = blockIdx.x % N_PHA;

    if (tid < 256) {
        float ang = (float)tid * (6.283185307179586f / 1024.0f);
        float s, c;
        sincosf(ang, &s, &c);
        tw[TA(tid)]     = c;
        tw[TA(tid) + 1] = s;
    }

    const float* xrow = x + bc * T_LEN;
    for (int i = tid; i < 512; i += 256)
        xe[i] = (i < 256) ? xrow[i] : xrow[3584 + i];   // x[0..255] | x[3840..]
    for (int i = tid; i < FIR_L; i += 256) {
        fb0[i] = filt[j * FIR_L + i];
        fb1[i] = filt[(j + N_PHA) * FIR_L + i];
    }
    __syncthreads();

    // ---- boundary corrections, fused uniform 257-iter loop (no divergence):
    // front (q < 256-tid): l=q,  x=xe[256+tid+q], f=fb[q]      -> corr[tid]
    // tail  (else):        j'=u-256, x=xe[j'],    f=fb[256+q]  -> corr[3840+tid]
    float cfa = 0.0f, cfb = 0.0f, cta = 0.0f, ctb = 0.0f;
#pragma unroll 1
    for (int q = 0; q <= 256; ++q) {
        const int  u   = tid + q;              // [0, 512)
        const int  xi  = (u + 256) & 511;
        const bool fr  = (u < 256);
        const int  fbi = fr ? q : q + 256;
        const float xv = xe[xi];
        const float f0 = fb0[fbi];
        const float f1 = fb1[fbi];
        const float xF = fr ? xv : 0.0f;
        const float xT = xv - xF;
        cfa = fmaf(f0, xF, cfa);  cta = fmaf(f0, xT, cta);
        cfb = fmaf(f1, xF, cfb);  ctb = fmaf(f1, xT, ctb);
    }
    __syncthreads();   // xe/fb reads done before z overwrite

    // stage packed corr_a + i*corr_b (zero middle)
    for (int i = tid; i < 4096; i += 256)
        *(float2*)&z[ZA(i)] = make_float2(0.0f, 0.0f);
    __syncthreads();
    *(float2*)&z[ZA(tid)]        = make_float2(-cfa, -cfb);
    *(float2*)&z[ZA(3840 + tid)] = make_float2(-cta, -ctb);
    __syncthreads();

    fft_fwd6(z, tw, tid);    // Z = Ca + i*Cb, digit-reversed storage

    // ---- half-spectrum Hermitian split + masked products
    const float2* Xrow = Xs + bc * 4096;
    const float2* H0r  = Hs + j * 4096;
    const float2* H1r  = Hs + (j + N_PHA) * 4096;
    const float inv_n = 1.0f / 4096.0f;
    float2 Pb[8];
    float2 PbN = make_float2(0.0f, 0.0f);
#pragma unroll 1
    for (int k = 0; k < 8; ++k) {
        const int f  = (k << 8) + tid;            // [0, 2048)
        const int g  = (4096 - f) & 4095;         // partner (f=0 -> self)
        const int si = ZA(digitrev12(f));
        const int sg = ZA(digitrev12(g));
        const float2 Zs = *(const float2*)&z[si];
        const float2 Zp = *(const float2*)&z[sg];
        const float Ax = 0.5f * (Zs.x + Zp.x), Ay = 0.5f * (Zs.y - Zp.y);
        const float Bx = 0.5f * (Zs.y + Zp.y), By = 0.5f * (Zp.x - Zs.x);
        const float2 X  = Xrow[f];
        const float2 H0 = H0r[f];
        const float2 H1 = H1r[f];
        const float mf = (f == 0) ? 1.0f : 2.0f;
        const float2 Pa = make_float2((X.x * H0.x - X.y * H0.y + Ax) * mf,
                                      (X.x * H0.y + X.y * H0.x + Ay) * mf);
        const float sb = mf * inv_n;              // fold 1/N into amp path
        Pb[k] = make_float2((X.x * H1.x - X.y * H1.y + Bx) * sb,
                            (X.x * H1.y + X.y * H1.x + By) * sb);
        *(float2*)&z[si] = Pa;
        if (f) *(float2*)&z[sg] = make_float2(0.0f, 0.0f);
    }
    const int siN = ZA(digitrev12(2048));
    if (tid == 0) {   // Nyquist (self-paired, mask=1)
        const float2 Zs = *(const float2*)&z[siN];
        const float2 X  = Xrow[2048];
        const float2 H0 = H0r[2048];
        const float2 H1 = H1r[2048];
        *(float2*)&z[siN] = make_float2(X.x * H0.x - X.y * H0.y + Zs.x,
                                        X.x * H0.y + X.y * H0.x);
        PbN = make_float2((X.x * H1.x - X.y * H1.y + Zs.y) * inv_n,
                          (X.x * H1.y + X.y * H1.x) * inv_n);
    }
    __syncthreads();

    // ---- band j (phase): inv FFT + atan2 emit
    fft_inv6(z, tw, tid);
    {
        float* dst = pha + (bc * N_PHA + j) * T_LEN;
        for (int i = tid; i < 4096; i += 256) {
            const float2 zz = *(const float2*)&z[ZA(i)];
            dst[i] = atan2f(zz.y, zz.x);         // 1/N scale cancels
        }
    }
    __syncthreads();   // emit reads done before overwriting z

    // ---- band j+10 (amplitude): stage Pb, inv FFT, |.| emit (bf16)
#pragma unroll 1
    for (int k = 0; k < 8; ++k) {
        const int f  = (k << 8) + tid;
        const int g  = (4096 - f) & 4095;
        *(float2*)&z[ZA(digitrev12(f))] = Pb[k];
        if (f) *(float2*)&z[ZA(digitrev12(g))] = make_float2(0.0f, 0.0f);
    }
    if (tid == 0) *(float2*)&z[siN] = PbN;
    __syncthreads();

    fft_inv6(z, tw, tid);
    {
        unsigned short* dst = amp_bf + (bc * N_AMP + j) * T_LEN;
        for (int i = tid; i < 4096; i += 256) {
            const float2 zz = *(const float2*)&z[ZA(i)];
            dst[i] = f2bf(sqrtf(zz.x * zz.x + zz.y * zz.y));   // scale folded
        }
    }
}

// ---------------------------------------------------------------------------
// Kernel 2: per (bc, pha-band): 3-hot soft phase binning + einsum via MFMA,
// in-block reduce + MI (unchanged from R8 — throughput-bound, known good).
// ---------------------------------------------------------------------------
__global__ __launch_bounds__(256) void bin_mi_mfma(
    const float* __restrict__ pha,             // (BC, 10, T) fp32
    const unsigned short* __restrict__ amp_bf, // (BC, 10, T) bf16 bits
    float* __restrict__ out)                   // (BC, 10, 10)
{
    const int tid  = threadIdx.x;
    const int lane = tid & 63;
    const int wv   = tid >> 6;        // 0..3
    const int bc   = blockIdx.x / N_PHA;
    const int p    = blockIdx.x % N_PHA;

    __shared__ unsigned int wbufW[4][18 * 68];  // per-wave, 128 samples + pad
    __shared__ float psum[4][11][N_BINS];
    __shared__ float asum[11][N_BINS];

    const float* phrow = pha + (bc * N_PHA + p) * T_LEN;
    const unsigned short* arow = amp_bf + bc * N_AMP * T_LEN;

    const float PI_F  = 3.14159274101257324f;
    const float INVD  = 2.8647889756541160f;   // 9/pi
    const float DELTA = 0.34906585039886590f;  // 2pi/18
    const float C1    = 12.184696791468343f;   // DELTA^2 / 0.01
    const float C2    = 69.813170079773180f;   // 2*DELTA / 0.01

    const int m_ = lane & 15;
    const int q_ = lane >> 4;
    const int n_ = lane & 15;

    short8 zero8;
#pragma unroll
    for (int k = 0; k < 8; ++k) zero8[k] = 0;
    short8 ones8;
#pragma unroll
    for (int k = 0; k < 8; ++k) ones8[k] = (short)0x3F80;   // bf16 1.0

    f32x4 acc0 = {0.f, 0.f, 0.f, 0.f};   // bins 0..15
    f32x4 acc1 = {0.f, 0.f, 0.f, 0.f};   // bins 16..17

    const int base_t = wv * 1024;
    unsigned short* wh = (unsigned short*)&wbufW[wv][0];

    // hoist all phase loads (issue early, independent)
    float2 pp[8];
#pragma unroll
    for (int c = 0; c < 8; ++c)
        pp[c] = *(const float2*)&phrow[base_t + c * 128 + lane * 2];

    for (int chunk = 0; chunk < 8; ++chunk) {
        const int cb = base_t + chunk * 128;

        // prefetch this chunk's A fragments (latency overlaps softmax below)
        short8 af[4];
#pragma unroll
        for (int s = 0; s < 4; ++s) {
            const int tA = cb + s * 32 + q_ * 8;
            if (m_ < N_AMP)       af[s] = *(const short8*)(arow + m_ * T_LEN + tA);
            else if (m_ == N_AMP) af[s] = ones8;
            else                  af[s] = zero8;
        }

        // zero this lane's column in all 18 rows
#pragma unroll
        for (int k = 0; k < N_BINS; ++k)
            wbufW[wv][k * 68 + lane] = 0u;

        // 3-hot softmax, two samples
#pragma unroll
        for (int h = 0; h < 2; ++h) {
            const float ph = h ? pp[chunk].y : pp[chunk].x;
            float u  = (ph + PI_F) * INVD;       // in [0, 18]
            float jf = floorf(u);
            float d  = (u - jf - 0.5f) * DELTA;
            int j0 = (int)jf;
            if (j0 >= N_BINS) j0 -= N_BINS;      // ph == +pi wraps
            const int jm = (j0 == 0) ? N_BINS - 1 : j0 - 1;
            const int jp = (j0 == N_BINS - 1) ? 0 : j0 + 1;
            const float em = expf(-C1 - C2 * d);
            const float ep = expf(-C1 + C2 * d);
            const float inv = 1.0f / (1.0f + em + ep);
            wh[(j0 * 68 + lane) * 2 + h] = f2bf(inv);
            wh[(jm * 68 + lane) * 2 + h] = f2bf(em * inv);
            wh[(jp * 68 + lane) * 2 + h] = f2bf(ep * inv);
        }
        __builtin_amdgcn_wave_barrier();   // pin: w stores before frag reads

        // ---- 4 MFMA K-steps (K=32 each)
#pragma unroll
        for (int s = 0; s < 4; ++s) {
            const int woff = s * 16 + q_ * 4;
            short8 bfrag0 = *(const short8*)&wbufW[wv][n_ * 68 + woff];
            short8 bfrag1 = (n_ < 2)
                ? *(const short8*)&wbufW[wv][(16 + n_) * 68 + woff]
                : zero8;
            acc0 = __builtin_amdgcn_mfma_f32_16x16x32_bf16(af[s], bfrag0, acc0, 0, 0, 0);
            acc1 = __builtin_amdgcn_mfma_f32_16x16x32_bf16(af[s], bfrag1, acc1, 0, 0, 0);
        }
        __builtin_amdgcn_wave_barrier();   // pin: frag reads before next zeroing
    }

    // ---- per-wave C tiles (C/D: col=lane&15, row=(lane>>4)*4+reg)
#pragma unroll
    for (int r = 0; r < 4; ++r) {
        const int m = q_ * 4 + r;
        if (m < 11) {
            psum[wv][m][n_] = acc0[r];
            if (n_ < 2) psum[wv][m][16 + n_] = acc1[r];
        }
    }
    __syncthreads();

    if (tid < 11 * N_BINS) {
        const int m = tid / N_BINS;
        const int k = tid % N_BINS;
        asum[m][k] = psum[0][m][k] + psum[1][m][k] + psum[2][m][k] + psum[3][m][k];
    }
    __syncthreads();

    if (tid < N_AMP) {
        float ma[N_BINS];
        float msum = 0.0f;
#pragma unroll
        for (int k = 0; k < N_BINS; ++k) {
            float m = asum[tid][k] / (asum[10][k] + 1e-8f);
            ma[k] = m;
            msum += m;
        }
        const float inv = 1.0f / (msum + 1e-8f);
        float acc = 0.0f;
#pragma unroll
        for (int k = 0; k < N_BINS; ++k) {
            float pk = ma[k] * inv;
            acc = fmaf(pk, logf(pk + 1e-8f), acc);
        }
        const float logk = 2.89037175789124f;    // log(18)
        out[(bc * N_PHA + p) * N_AMP + tid] = (logk + acc) / logk;
    }
}

extern "C" void kernel_launch(void* const* d_in, const int* in_sizes, int n_in,
                              void* d_out, int out_size, void* d_ws, size_t ws_size,
                              hipStream_t stream) {
    const float* x    = (const float*)d_in[0];   // (4,16,4096) f32
    const float* filt = (const float*)d_in[1];   // (20,513) f32
    float* out = (float*)d_out;                  // (4,16,10,10) f32

    // ws layout: pha fp32 | amp bf16 | Xspec | Hspec  (~18.5 MB)
    float* pha = (float*)d_ws;                               // BC*10*T fp32
    unsigned short* amp_bf = (unsigned short*)(pha + BC * N_PHA * T_LEN);
    float2* Xs = (float2*)(amp_bf + BC * N_AMP * T_LEN);     // BC*4096 cplx
    float2* Hs = Xs + BC * 4096;                             // 20*4096 cplx

    spectral_pre <<<BC + N_BANDS, 256, 0, stream>>>(x, filt, Xs, Hs);
    spectral_main<<<BC * N_PHA,   256, 0, stream>>>(x, filt, Xs, Hs, pha, amp_bf);
    bin_mi_mfma  <<<BC * N_PHA,   256, 0, stream>>>(pha, amp_bf, out);
}

// Round 10
// 148.091 us; speedup vs baseline: 1.0825x; 1.0825x over previous
//
#include <hip/hip_runtime.h>
#include <math.h>

// Problem constants (match reference)
#define T_LEN 4096
#define FIR_L 513
#define N_PHA 10
#define N_AMP 10
#define N_BANDS 20
#define N_BINS 18
#define BC 64            // B*C = 4*16

typedef __attribute__((ext_vector_type(8))) short short8;
typedef __attribute__((ext_vector_type(4))) float f32x4;

// Interleaved-complex skewed addresses (float index of re; im at +1).
// Extents: ZA(4095)+2 = 8702 -> z region 8704 floats; TA(1023)+2 = 2174 -> 2176.
#define ZA(i) (((i) << 1) + ((((i) >> 4)) << 1))
#define TA(m) (((m) << 1) + ((((m) >> 4)) << 1))

// float -> bf16 round-to-nearest-even
static __device__ __forceinline__ unsigned short f2bf(float x) {
    unsigned u = __float_as_uint(x);
    unsigned r = u + 0x7FFFu + ((u >> 16) & 1u);
    return (unsigned short)(r >> 16);
}

// storage index <-> frequency after radix-4 DIF (base-4 digit reversal, involution)
static __device__ __forceinline__ int digitrev12(int p) {
    unsigned rr = __brev((unsigned)p) >> 20;               // 12-bit bit reversal
    rr = ((rr & 0x555u) << 1) | ((rr & 0xAAAu) >> 1);      // swap bit pairs
    return (int)rr;
}

// Forward radix-4 DIF, natural -> base-4 digit-reversed. tw[m]=(c,s) m<1024.
template<int TPB>
static __device__ __forceinline__ void fft_fwd6(float* z, const float* tw, int tid) {
    for (int s = 0; s < 6; ++s) {
        const int hl = 10 - 2 * s;
        const int h  = 1 << hl;
#pragma unroll
        for (int r = 0; r < 1024 / TPB; ++r) {
            const int u  = tid + r * TPB;
            const int k  = u & (h - 1);
            const int g  = u >> hl;
            const int i0 = (g << (hl + 2)) + k;
            const int m1 = k << (2 * s);                 // < 1024
            const float2 w1 = *(const float2*)&tw[TA(m1)];
            const float c1 = w1.x, s1 = w1.y;
            const float s2 = 2.0f * s1 * c1;             // double angle
            const float c2 = fmaf(-2.0f * s1, s1, 1.0f);
            const float c3 = c1 * c2 - s1 * s2;          // angle sum
            const float s3 = s1 * c2 + c1 * s2;

            float2 a = *(const float2*)&z[ZA(i0)];
            float2 b = *(const float2*)&z[ZA(i0 + h)];
            float2 c = *(const float2*)&z[ZA(i0 + 2 * h)];
            float2 d = *(const float2*)&z[ZA(i0 + 3 * h)];

            const float t0r = a.x + c.x, t0i = a.y + c.y;
            const float t1r = a.x - c.x, t1i = a.y - c.y;
            const float t2r = b.x + d.x, t2i = b.y + d.y;
            const float t3r = b.x - d.x, t3i = b.y - d.y;

            const float y0r = t0r + t2r,  y0i = t0i + t2i;
            const float u1r = t1r + t3i, u1i = t1i - t3r;   // t1 - i*t3
            const float u2r = t0r - t2r, u2i = t0i - t2i;
            const float u3r = t1r - t3i, u3i = t1i + t3r;   // t1 + i*t3
            const float y1r = u1r * c1 + u1i * s1, y1i = u1i * c1 - u1r * s1;
            const float y2r = u2r * c2 + u2i * s2, y2i = u2i * c2 - u2r * s2;
            const float y3r = u3r * c3 + u3i * s3, y3i = u3i * c3 - u3r * s3;

            *(float2*)&z[ZA(i0)]         = make_float2(y0r, y0i);
            *(float2*)&z[ZA(i0 + h)]     = make_float2(y1r, y1i);
            *(float2*)&z[ZA(i0 + 2 * h)] = make_float2(y2r, y2i);
            *(float2*)&z[ZA(i0 + 3 * h)] = make_float2(y3r, y3i);
        }
        __syncthreads();
    }
}

// Inverse radix-4 DIT, base-4 digit-reversed -> natural (unscaled).
template<int TPB>
static __device__ __forceinline__ void fft_inv6(float* z, const float* tw, int tid) {
    for (int s = 0; s < 6; ++s) {
        const int hl = 2 * s;
        const int L  = 1 << hl;
#pragma unroll
        for (int r = 0; r < 1024 / TPB; ++r) {
            const int u  = tid + r * TPB;
            const int k  = u & (L - 1);
            const int g  = u >> hl;
            const int i0 = (g << (hl + 2)) + k;
            const int m1 = k << (10 - hl);               // < 1024
            const float2 w1 = *(const float2*)&tw[TA(m1)];
            const float c1 = w1.x, s1 = w1.y;
            const float s2 = 2.0f * s1 * c1;
            const float c2 = fmaf(-2.0f * s1, s1, 1.0f);
            const float c3 = c1 * c2 - s1 * s2;
            const float s3 = s1 * c2 + c1 * s2;

            float2 a = *(const float2*)&z[ZA(i0)];
            float2 b = *(const float2*)&z[ZA(i0 + L)];
            float2 c = *(const float2*)&z[ZA(i0 + 2 * L)];
            float2 d = *(const float2*)&z[ZA(i0 + 3 * L)];

            const float tbr = b.x * c1 - b.y * s1, tbi = b.y * c1 + b.x * s1;
            const float tcr = c.x * c2 - c.y * s2, tci = c.y * c2 + c.x * s2;
            const float tdr = d.x * c3 - d.y * s3, tdi = d.y * c3 + d.x * s3;

            const float y0r = a.x + tbr + tcr + tdr;
            const float y0i = a.y + tbi + tci + tdi;
            const float y1r = a.x - tbi - tcr + tdi;
            const float y1i = a.y + tbr - tci - tdr;
            const float y2r = a.x - tbr + tcr - tdr;
            const float y2i = a.y - tbi + tci - tdi;
            const float y3r = a.x + tbi - tcr - tdi;
            const float y3i = a.y - tbr - tci + tdr;

            *(float2*)&z[ZA(i0)]         = make_float2(y0r, y0i);
            *(float2*)&z[ZA(i0 + L)]     = make_float2(y1r, y1i);
            *(float2*)&z[ZA(i0 + 2 * L)] = make_float2(y2r, y2i);
            *(float2*)&z[ZA(i0 + 3 * L)] = make_float2(y3r, y3i);
        }
        __syncthreads();
    }
}

// ---------------------------------------------------------------------------
// Precompute: blocks 0..63 -> X[bc]; blocks 64..83 -> Hf[band] (corr kernel
// h[n]=f[256-n] circular). Spectra stored in NATURAL frequency order.
// 512 threads (8 waves): halves per-stage serial depth on this
// latency-bound, 84-block launch.
// ---------------------------------------------------------------------------
__global__ __launch_bounds__(512) void spectral_pre(
    const float* __restrict__ x,      // (BC, T)
    const float* __restrict__ filt,   // (20, 513)
    float2* __restrict__ Xs,          // (BC, 4096) natural freq order
    float2* __restrict__ Hs)          // (20, 4096) natural freq order
{
    __shared__ float smem[10880];
    __shared__ float fb[FIR_L];
    float* z  = smem;
    float* tw = smem + 8704;

    const int tid = threadIdx.x;
    const int b   = blockIdx.x;

    for (int m = tid; m < 1024; m += 512) {
        float ang = (float)m * (6.283185307179586f / 4096.0f);
        float s, c;
        sincosf(ang, &s, &c);
        tw[TA(m)]     = c;
        tw[TA(m) + 1] = s;
    }

    if (b < BC) {
        const float* xrow = x + b * T_LEN;
        for (int i = tid; i < 4096; i += 512)
            *(float2*)&z[ZA(i)] = make_float2(xrow[i], 0.0f);
    } else {
        const float* frow = filt + (b - BC) * FIR_L;
        for (int i = tid; i < FIR_L; i += 512) fb[i] = frow[i];
        __syncthreads();
        for (int i = tid; i < 4096; i += 512) {
            float hv = 0.0f;
            if (i < 257)        hv = fb[256 - i];
            else if (i >= 3840) hv = fb[4352 - i];
            *(float2*)&z[ZA(i)] = make_float2(hv, 0.0f);
        }
    }
    __syncthreads();

    fft_fwd6<512>(z, tw, tid);

    float2* dst = (b < BC) ? (Xs + b * 4096) : (Hs + (b - BC) * 4096);
    for (int i = tid; i < 4096; i += 512)
        dst[digitrev12(i)] = *(const float2*)&z[ZA(i)];   // natural order
}

// ---------------------------------------------------------------------------
// Main (exact R8 structure, measured 73.4 us): per (bc, band-pair j/j+10):
// pack corr_a + i*corr_b into ONE fwd FFT; half-spectrum Hermitian split +
// masked products (Pb in 16 VGPRs); two inverse FFTs.
// ---------------------------------------------------------------------------
__global__ __launch_bounds__(256) void spectral_main(
    const float* __restrict__ x,          // (BC, T)
    const float* __restrict__ filt,       // (20, 513)
    const float2* __restrict__ Xs,        // (BC, 4096) natural order
    const float2* __restrict__ Hs,        // (20, 4096) natural order
    float* __restrict__ pha,              // (BC, 10, T) fp32
    unsigned short* __restrict__ amp_bf)  // (BC, 10, T) bf16 bits
{
    __shared__ float smem[10880];   // z [0,8704), tw [8704,10880)
    __shared__ float xe[512];       // x[0..255] | x[3840..4095]
    __shared__ float fb0[FIR_L];    // band j (phase)
    __shared__ float fb1[FIR_L];    // band j+10 (amp)
    float* z  = smem;
    float* tw = smem + 8704;

    const int tid = threadIdx.x;
    const int bc  = blockIdx.x / N_PHA;
    const int j   = blockIdx.x % N_PHA;

    for (int m = tid; m < 1024; m += 256) {
        float ang = (float)m * (6.283185307179586f / 4096.0f);
        float s, c;
        sincosf(ang, &s, &c);
        tw[TA(m)]     = c;
        tw[TA(m) + 1] = s;
    }

    const float* xrow = x + bc * T_LEN;
    for (int i = tid; i < 512; i += 256)
        xe[i] = (i < 256) ? xrow[i] : xrow[3584 + i];
    for (int i = tid; i < FIR_L; i += 256) {
        fb0[i] = filt[j * FIR_L + i];
        fb1[i] = filt[(j + N_PHA) * FIR_L + i];
    }
    __syncthreads();

    // ---- boundary corrections for both bands (shared xe reads)
    float cfa = 0.0f, cfb = 0.0f, cta = 0.0f, ctb = 0.0f;
    for (int l = 0; l <= 255 - tid; ++l) {
        const float xv = xe[256 + tid + l];
        cfa = fmaf(fb0[l], xv, cfa);
        cfb = fmaf(fb1[l], xv, cfb);
    }
    for (int jj = 0; jj <= tid; ++jj) {
        const float xv = xe[jj];
        cta = fmaf(fb0[512 - tid + jj], xv, cta);
        ctb = fmaf(fb1[512 - tid + jj], xv, ctb);
    }

    // stage packed corr_a + i*corr_b (zero middle)
    for (int i = tid; i < 4096; i += 256)
        *(float2*)&z[ZA(i)] = make_float2(0.0f, 0.0f);
    *(float2*)&z[ZA(tid)]        = make_float2(-cfa, -cfb);
    *(float2*)&z[ZA(3840 + tid)] = make_float2(-cta, -ctb);
    __syncthreads();

    fft_fwd6<256>(z, tw, tid);    // Z = Ca + i*Cb, digit-reversed storage

    // ---- half-spectrum Hermitian split + masked products
    const float2* Xrow = Xs + bc * 4096;
    const float2* H0r  = Hs + j * 4096;
    const float2* H1r  = Hs + (j + N_PHA) * 4096;
    const float inv_n = 1.0f / 4096.0f;
    float2 Pb[8];
    float2 PbN = make_float2(0.0f, 0.0f);
#pragma unroll 1
    for (int k = 0; k < 8; ++k) {
        const int f  = (k << 8) + tid;            // [0, 2048)
        const int g  = (4096 - f) & 4095;         // partner (f=0 -> self)
        const int si = ZA(digitrev12(f));
        const int sg = ZA(digitrev12(g));
        const float2 Zs = *(const float2*)&z[si];
        const float2 Zp = *(const float2*)&z[sg];
        const float Ax = 0.5f * (Zs.x + Zp.x), Ay = 0.5f * (Zs.y - Zp.y);
        const float Bx = 0.5f * (Zs.y + Zp.y), By = 0.5f * (Zp.x - Zs.x);
        const float2 X  = Xrow[f];
        const float2 H0 = H0r[f];
        const float2 H1 = H1r[f];
        const float mf = (f == 0) ? 1.0f : 2.0f;
        const float2 Pa = make_float2((X.x * H0.x - X.y * H0.y + Ax) * mf,
                                      (X.x * H0.y + X.y * H0.x + Ay) * mf);
        const float sb = mf * inv_n;              // fold 1/N into amp path
        Pb[k] = make_float2((X.x * H1.x - X.y * H1.y + Bx) * sb,
                            (X.x * H1.y + X.y * H1.x + By) * sb);
        *(float2*)&z[si] = Pa;
        if (f) *(float2*)&z[sg] = make_float2(0.0f, 0.0f);
    }
    const int siN = ZA(digitrev12(2048));
    if (tid == 0) {   // Nyquist (self-paired, mask=1)
        const float2 Zs = *(const float2*)&z[siN];
        const float2 X  = Xrow[2048];
        const float2 H0 = H0r[2048];
        const float2 H1 = H1r[2048];
        *(float2*)&z[siN] = make_float2(X.x * H0.x - X.y * H0.y + Zs.x,
                                        X.x * H0.y + X.y * H0.x);
        PbN = make_float2((X.x * H1.x - X.y * H1.y + Zs.y) * inv_n,
                          (X.x * H1.y + X.y * H1.x) * inv_n);
    }
    __syncthreads();

    // ---- band j (phase): inv FFT + atan2 emit
    fft_inv6<256>(z, tw, tid);
    {
        float* dst = pha + (bc * N_PHA + j) * T_LEN;
        for (int i = tid; i < 4096; i += 256) {
            const float2 zz = *(const float2*)&z[ZA(i)];
            dst[i] = atan2f(zz.y, zz.x);         // 1/N scale cancels
        }
    }
    __syncthreads();   // emit reads done before overwriting z

    // ---- band j+10 (amplitude): stage Pb, inv FFT, |.| emit (bf16)
#pragma unroll 1
    for (int k = 0; k < 8; ++k) {
        const int f  = (k << 8) + tid;
        const int g  = (4096 - f) & 4095;
        *(float2*)&z[ZA(digitrev12(f))] = Pb[k];
        if (f) *(float2*)&z[ZA(digitrev12(g))] = make_float2(0.0f, 0.0f);
    }
    if (tid == 0) *(float2*)&z[siN] = PbN;
    __syncthreads();

    fft_inv6<256>(z, tw, tid);
    {
        unsigned short* dst = amp_bf + (bc * N_AMP + j) * T_LEN;
        for (int i = tid; i < 4096; i += 256) {
            const float2 zz = *(const float2*)&z[ZA(i)];
            dst[i] = f2bf(sqrtf(zz.x * zz.x + zz.y * zz.y));   // scale folded
        }
    }
}

// ---------------------------------------------------------------------------
// Kernel 2: per (bc, pha-band): 3-hot soft phase binning + einsum via MFMA.
// v2: chunk=256 samples/wave (4 round-trips instead of 8), b128 zeroing
// (10 stores vs 144 b32-issues per chunk-pair), exp2f with folded log2e.
// wbuf row stride 132 words (non-pow2 -> banks spread). LDS ~43 KB ->
// 3 blocks/CU; grid 640 needs 2.5/CU -> all blocks still co-resident.
// ---------------------------------------------------------------------------
__global__ __launch_bounds__(256) void bin_mi_mfma(
    const float* __restrict__ pha,             // (BC, 10, T) fp32
    const unsigned short* __restrict__ amp_bf, // (BC, 10, T) bf16 bits
    float* __restrict__ out)                   // (BC, 10, 10)
{
    const int tid  = threadIdx.x;
    const int lane = tid & 63;
    const int wv   = tid >> 6;        // 0..3
    const int bc   = blockIdx.x / N_PHA;
    const int p    = blockIdx.x % N_PHA;

    // per-wave w buffer: 18 rows x 132 words (264 halfwords = 256 samples + pad)
    __shared__ __align__(16) unsigned int wbufW[4][2432];   // 608 float4 slots
    __shared__ float psum[4][11][N_BINS];
    __shared__ float asum[11][N_BINS];

    const float* phrow = pha + (bc * N_PHA + p) * T_LEN;
    const unsigned short* arow = amp_bf + bc * N_AMP * T_LEN;

    const float PI_F  = 3.14159274101257324f;
    const float INVD  = 2.8647889756541160f;   // 9/pi
    const float DELTA = 0.34906585039886590f;  // 2pi/18
    // exp(-C1 -/+ C2*d) = exp2(A1 -/+ B2*d), log2e folded:
    const float A1 = -17.578802243205334f;     // -C1*log2(e)
    const float B2 = 100.71909662928986f;      //  C2*log2(e)

    const int m_ = lane & 15;
    const int q_ = lane >> 4;
    const int n_ = lane & 15;

    short8 zero8;
#pragma unroll
    for (int k = 0; k < 8; ++k) zero8[k] = 0;
    short8 ones8;
#pragma unroll
    for (int k = 0; k < 8; ++k) ones8[k] = (short)0x3F80;   // bf16 1.0

    f32x4 acc0 = {0.f, 0.f, 0.f, 0.f};   // bins 0..15
    f32x4 acc1 = {0.f, 0.f, 0.f, 0.f};   // bins 16..17

    const int base_t = wv * 1024;
    unsigned short* wh = (unsigned short*)&wbufW[wv][0];
    float4* wz = (float4*)&wbufW[wv][0];

    // hoist all phase loads (4 chunks x 4 samples/lane)
    float4 pp[4];
#pragma unroll
    for (int c = 0; c < 4; ++c)
        pp[c] = *(const float4*)&phrow[base_t + c * 256 + lane * 4];

    for (int chunk = 0; chunk < 4; ++chunk) {
        const int cb = base_t + chunk * 256;

        // prefetch this chunk's A fragments (latency overlaps softmax below)
        short8 af[8];
#pragma unroll
        for (int s = 0; s < 8; ++s) {
            const int tA = cb + s * 32 + q_ * 8;
            if (m_ < N_AMP)       af[s] = *(const short8*)(arow + m_ * T_LEN + tA);
            else if (m_ == N_AMP) af[s] = ones8;
            else                  af[s] = zero8;
        }

        // zero this wave's wbuf: 608 float4 slots across 64 lanes
#pragma unroll
        for (int it = 0; it < 10; ++it) {
            const int slot = lane + (it << 6);
            if (it < 9 || slot < 608)
                wz[slot] = make_float4(0.f, 0.f, 0.f, 0.f);
        }

        // 3-hot softmax, four samples
        const float* pv = (const float*)&pp[chunk];
#pragma unroll
        for (int h = 0; h < 4; ++h) {
            const float ph = pv[h];
            float u  = (ph + PI_F) * INVD;       // in [0, 18]
            float jf = floorf(u);
            float d  = (u - jf - 0.5f) * DELTA;
            int j0 = (int)jf;
            if (j0 >= N_BINS) j0 -= N_BINS;      // ph == +pi wraps
            const int jm = (j0 == 0) ? N_BINS - 1 : j0 - 1;
            const int jp = (j0 == N_BINS - 1) ? 0 : j0 + 1;
            const float em = exp2f(fmaf(-B2, d, A1));
            const float ep = exp2f(fmaf( B2, d, A1));
            const float inv = 1.0f / (1.0f + em + ep);
            const int idx = lane * 4 + h;        // halfword sample index
            wh[j0 * 264 + idx] = f2bf(inv);
            wh[jm * 264 + idx] = f2bf(em * inv);
            wh[jp * 264 + idx] = f2bf(ep * inv);
        }
        __builtin_amdgcn_wave_barrier();   // pin: w stores before frag reads

        // ---- 8 MFMA K-steps (K=32 each)
#pragma unroll
        for (int s = 0; s < 8; ++s) {
            const int woff = s * 16 + q_ * 4;
            short8 bfrag0 = *(const short8*)&wbufW[wv][n_ * 132 + woff];
            short8 bfrag1 = (n_ < 2)
                ? *(const short8*)&wbufW[wv][(16 + n_) * 132 + woff]
                : zero8;
            acc0 = __builtin_amdgcn_mfma_f32_16x16x32_bf16(af[s], bfrag0, acc0, 0, 0, 0);
            acc1 = __builtin_amdgcn_mfma_f32_16x16x32_bf16(af[s], bfrag1, acc1, 0, 0, 0);
        }
        __builtin_amdgcn_wave_barrier();   // pin: frag reads before next zeroing
    }

    // ---- per-wave C tiles (C/D: col=lane&15, row=(lane>>4)*4+reg)
#pragma unroll
    for (int r = 0; r < 4; ++r) {
        const int m = q_ * 4 + r;
        if (m < 11) {
            psum[wv][m][n_] = acc0[r];
            if (n_ < 2) psum[wv][m][16 + n_] = acc1[r];
        }
    }
    __syncthreads();

    if (tid < 11 * N_BINS) {
        const int m = tid / N_BINS;
        const int k = tid % N_BINS;
        asum[m][k] = psum[0][m][k] + psum[1][m][k] + psum[2][m][k] + psum[3][m][k];
    }
    __syncthreads();

    if (tid < N_AMP) {
        float ma[N_BINS];
        float msum = 0.0f;
#pragma unroll
        for (int k = 0; k < N_BINS; ++k) {
            float m = asum[tid][k] / (asum[10][k] + 1e-8f);
            ma[k] = m;
            msum += m;
        }
        const float inv = 1.0f / (msum + 1e-8f);
        float acc = 0.0f;
#pragma unroll
        for (int k = 0; k < N_BINS; ++k) {
            float pk = ma[k] * inv;
            acc = fmaf(pk, logf(pk + 1e-8f), acc);
        }
        const float logk = 2.89037175789124f;    // log(18)
        out[(bc * N_PHA + p) * N_AMP + tid] = (logk + acc) / logk;
    }
}

extern "C" void kernel_launch(void* const* d_in, const int* in_sizes, int n_in,
                              void* d_out, int out_size, void* d_ws, size_t ws_size,
                              hipStream_t stream) {
    const float* x    = (const float*)d_in[0];   // (4,16,4096) f32
    const float* filt = (const float*)d_in[1];   // (20,513) f32
    float* out = (float*)d_out;                  // (4,16,10,10) f32

    // ws layout: pha fp32 | amp bf16 | Xspec | Hspec  (~18.5 MB)
    float* pha = (float*)d_ws;                               // BC*10*T fp32
    unsigned short* amp_bf = (unsigned short*)(pha + BC * N_PHA * T_LEN);
    float2* Xs = (float2*)(amp_bf + BC * N_AMP * T_LEN);     // BC*4096 cplx
    float2* Hs = Xs + BC * 4096;                             // 20*4096 cplx

    spectral_pre <<<BC + N_BANDS, 512, 0, stream>>>(x, filt, Xs, Hs);
    spectral_main<<<BC * N_PHA,   256, 0, stream>>>(x, filt, Xs, Hs, pha, amp_bf);
    bin_mi_mfma  <<<BC * N_PHA,   256, 0, stream>>>(pha, amp_bf, out);
}